// Round 7
// baseline (297.899 us; speedup 1.0000x reference)
//
#include <hip/hip_runtime.h>
#include <stdint.h>

typedef unsigned short u16;
typedef unsigned int   u32;
typedef __attribute__((ext_vector_type(8))) short bf16x8;   // 8 bf16 (4 VGPRs)
typedef __attribute__((ext_vector_type(4))) float f32x4;    // MFMA C/D
typedef __attribute__((ext_vector_type(4))) u32 u32x4;
typedef __attribute__((ext_vector_type(2))) u32 u32x2;

#define N_NODES 30000
#define N_EDGES 60000
#define A_DEG   6
#define D_DEG   16
#define BATCH   4096
#define FEAT    256
#define APAD    8     // LDS pad: (256+8)*2 = 528 B row stride (16B-aligned)

// ---------- bit helpers ----------
__device__ __forceinline__ float bfbits2f(u32 hi){ union{u32 u; float f;} v; v.u = hi; return v.f; }
__device__ __forceinline__ float bf2f(u16 h){ return bfbits2f(((u32)h)<<16); }
__device__ __forceinline__ float u2f(u32 u){ union{u32 u; float f;} v; v.u = u; return v.f; }
__device__ __forceinline__ u32 f2u(float f){ union{float f; u32 u;} v; v.f = f; return v.u; }
__device__ __forceinline__ u16 f2bf(float f){
  u32 u = f2u(f);
  return (u16)((u + 0x7fffu + ((u>>16)&1u)) >> 16);   // RTNE
}

struct F4 { float x,y,z,w; };
struct F8 { float v[8]; };

__device__ __forceinline__ F4 load4(const float* p){
  float4 t = *reinterpret_cast<const float4*>(p);
  F4 f; f.x=t.x; f.y=t.y; f.z=t.z; f.w=t.w; return f;
}
__device__ __forceinline__ F4 load4(const u16* p){
  uint2 u = *reinterpret_cast<const uint2*>(p);
  F4 f;
  f.x = bfbits2f(u.x<<16);
  f.y = bfbits2f(u.x & 0xffff0000u);
  f.z = bfbits2f(u.y<<16);
  f.w = bfbits2f(u.y & 0xffff0000u);
  return f;
}
// nontemporal variants: single-use streams, don't pollute L2/L3
__device__ __forceinline__ F4 ntload4(const float* p){
  u32x4 t = __builtin_nontemporal_load(reinterpret_cast<const u32x4*>(p));
  F4 f; f.x=u2f(t.x); f.y=u2f(t.y); f.z=u2f(t.z); f.w=u2f(t.w); return f;
}
__device__ __forceinline__ F4 ntload4(const u16* p){
  u32x2 t = __builtin_nontemporal_load(reinterpret_cast<const u32x2*>(p));
  F4 f;
  f.x = bfbits2f(t.x<<16);
  f.y = bfbits2f(t.x & 0xffff0000u);
  f.z = bfbits2f(t.y<<16);
  f.w = bfbits2f(t.y & 0xffff0000u);
  return f;
}
__device__ __forceinline__ F8 load8(const float* p){
  float4 a = *reinterpret_cast<const float4*>(p);
  float4 b = *reinterpret_cast<const float4*>(p+4);
  F8 f; f.v[0]=a.x; f.v[1]=a.y; f.v[2]=a.z; f.v[3]=a.w;
        f.v[4]=b.x; f.v[5]=b.y; f.v[6]=b.z; f.v[7]=b.w; return f;
}
__device__ __forceinline__ F8 ntload8(const float* p){
  u32x4 a = __builtin_nontemporal_load(reinterpret_cast<const u32x4*>(p));
  u32x4 b = __builtin_nontemporal_load(reinterpret_cast<const u32x4*>(p+4));
  F8 f; f.v[0]=u2f(a.x); f.v[1]=u2f(a.y); f.v[2]=u2f(a.z); f.v[3]=u2f(a.w);
        f.v[4]=u2f(b.x); f.v[5]=u2f(b.y); f.v[6]=u2f(b.z); f.v[7]=u2f(b.w); return f;
}
__device__ __forceinline__ F8 load8(const u16* p){
  uint4 u = *reinterpret_cast<const uint4*>(p);
  F8 f;
  f.v[0]=bfbits2f(u.x<<16); f.v[1]=bfbits2f(u.x&0xffff0000u);
  f.v[2]=bfbits2f(u.y<<16); f.v[3]=bfbits2f(u.y&0xffff0000u);
  f.v[4]=bfbits2f(u.z<<16); f.v[5]=bfbits2f(u.z&0xffff0000u);
  f.v[6]=bfbits2f(u.w<<16); f.v[7]=bfbits2f(u.w&0xffff0000u);
  return f;
}
// accumulate o[0..7] += ww * bf16x8(bits)
__device__ __forceinline__ void acc8(float* o, uint4 u, float ww){
  o[0] += ww*bfbits2f(u.x<<16); o[1] += ww*bfbits2f(u.x&0xffff0000u);
  o[2] += ww*bfbits2f(u.y<<16); o[3] += ww*bfbits2f(u.y&0xffff0000u);
  o[4] += ww*bfbits2f(u.z<<16); o[5] += ww*bfbits2f(u.z&0xffff0000u);
  o[6] += ww*bfbits2f(u.w<<16); o[7] += ww*bfbits2f(u.w&0xffff0000u);
}
__device__ __forceinline__ void store_bf8(u16* p, const float* f){
  uint4 u;
  u.x = (u32)f2bf(f[0]) | ((u32)f2bf(f[1])<<16);
  u.y = (u32)f2bf(f[2]) | ((u32)f2bf(f[3])<<16);
  u.z = (u32)f2bf(f[4]) | ((u32)f2bf(f[5])<<16);
  u.w = (u32)f2bf(f[6]) | ((u32)f2bf(f[7])<<16);
  *reinterpret_cast<uint4*>(p) = u;
}
// nontemporal 8-float store (final output, never re-read)
__device__ __forceinline__ void ntstore8(float* p, const float* f){
  u32x4 a, b;
  a.x=f2u(f[0]); a.y=f2u(f[1]); a.z=f2u(f[2]); a.w=f2u(f[3]);
  b.x=f2u(f[4]); b.y=f2u(f[5]); b.z=f2u(f[6]); b.w=f2u(f[7]);
  __builtin_nontemporal_store(a, reinterpret_cast<u32x4*>(p));
  __builtin_nontemporal_store(b, reinterpret_cast<u32x4*>(p+4));
}

__device__ __forceinline__ float eluf(float x){ return x > 0.f ? x : (__expf(x) - 1.f); }
__device__ __forceinline__ float lrelu(float x){ return x > 0.f ? x : 0.2f*x; }

__device__ __forceinline__ float wave_sum_lane0(float v){
  #pragma unroll
  for (int off = 32; off > 0; off >>= 1) v += __shfl_down(v, off, 64);
  return v;
}
__device__ __forceinline__ float half_sum_all(float v){   // reduce within 32-lane half
  #pragma unroll
  for (int off = 1; off < 32; off <<= 1) v += __shfl_xor(v, off, 64);
  return v;
}

// ---------- merged prep: z=0/1 -> weight transpose W1/W2; z=2 -> both wvecs ----------
__global__ __launch_bounds__(256) void prep_k(
    const float* __restrict__ Wn1, u16* __restrict__ Wt1,
    const float* __restrict__ Wn2, u16* __restrict__ Wt2,
    const float* __restrict__ We1, const float* __restrict__ ae1, float* __restrict__ wE1,
    const float* __restrict__ We2, const float* __restrict__ ae2, float* __restrict__ wE2)
{
  if (blockIdx.z < 2){
    const float* W = blockIdx.z ? Wn2 : Wn1;
    u16* Wt        = blockIdx.z ? Wt2 : Wt1;
    __shared__ float T[32][33];
    const int bx = blockIdx.x;   // k-tile
    const int by = blockIdx.y;   // n-tile
    const int tc = threadIdx.x & 31;
    const int tr = threadIdx.x >> 5;
    #pragma unroll
    for (int i=0;i<4;i++){
      int r = tr + i*8;
      T[r][tc] = W[(bx*32 + r)*FEAT + by*32 + tc];
    }
    __syncthreads();
    #pragma unroll
    for (int i=0;i<4;i++){
      int r = tr + i*8;
      Wt[(by*32 + r)*FEAT + bx*32 + tc] = f2bf(T[tc][r]);
    }
  } else {
    const int vb   = blockIdx.y*8 + blockIdx.x;       // 0..63
    const int lane = threadIdx.x & 63;
    const int row  = vb*4 + (threadIdx.x >> 6);
    const int c    = lane*4;
    {
      F4 h = load4(We1 + (long)row*FEAT + c);
      F4 a = load4(ae1 + c);
      float p = wave_sum_lane0(h.x*a.x + h.y*a.y + h.z*a.z + h.w*a.w);
      if (lane == 0) wE1[row] = p;
    }
    {
      F4 h = load4(We2 + (long)row*FEAT + c);
      F4 a = load4(ae2 + c);
      float p = wave_sum_lane0(h.x*a.x + h.y*a.y + h.z*a.z + h.w*a.w);
      if (lane == 0) wE2[row] = p;
    }
  }
}

// ---------- sb1: streaming matvec seb1[e] = edge_embs[e,:] . wE1 ----------
// Bit-identical summation order to the previous in-kernel computation.
__global__ __launch_bounds__(256) void sb1_k(const float* __restrict__ Xe,
    const float* __restrict__ wE, float* __restrict__ seb)
{
  const int tid = threadIdx.x;
  const int hl  = tid & 31;
  const int e   = blockIdx.x*8 + (tid >> 5);
  const int c   = hl*8;
  F8 x = ntload8(Xe + (long)e*FEAT + c);
  F8 v = load8(wE + c);
  float p = 0.f;
  #pragma unroll
  for (int j=0;j<8;j++) p += x.v[j]*v.v[j];
  p = half_sum_all(p);
  if (hl == 0) seb[e] = p;
}

// ---------- MFMA GEMM (64-row tile, 256 threads / 4 waves) + fused rowdots ----------
// Y[M,256](bf16) = X[M,256] @ W via Wt[n][k]; hg=Y·v1, snb=Y·v2.
// Staging loads are nontemporal (X is single-use stream).
template<typename TIN>
__global__ __launch_bounds__(256) void gemm_mfma_k(
    const TIN* __restrict__ X, const u16* __restrict__ Wt,
    const float* __restrict__ v1, const float* __restrict__ v2,
    u16* __restrict__ Y, float* __restrict__ hg, float* __restrict__ snb,
    int M)
{
  __shared__ u16 As[64][FEAT + APAD];
  __shared__ float hgs[64], sns[64];
  const int tid = threadIdx.x;
  const long row0 = (long)blockIdx.x * 64;

  if (tid < 64){ hgs[tid] = 0.f; sns[tid] = 0.f; }

  {
    const int c = (tid & 15) << 4;
    #pragma unroll
    for (int i=0;i<4;i++){
      const int r = (tid >> 4) + 16*i;
      u16* dst = &As[r][c];
      if (row0 + r < M){
        const TIN* src = X + (row0 + r)*FEAT + c;
        #pragma unroll
        for (int j=0;j<4;j++){
          F4 v = ntload4(src + 4*j);
          dst[4*j+0]=f2bf(v.x); dst[4*j+1]=f2bf(v.y);
          dst[4*j+2]=f2bf(v.z); dst[4*j+3]=f2bf(v.w);
        }
      } else {
        #pragma unroll
        for (int j=0;j<16;j++) dst[j] = 0;
      }
    }
  }
  __syncthreads();

  const int wave = tid >> 6;
  const int lane = tid & 63;
  const int l15  = lane & 15;
  const int kg   = lane >> 4;

  f32x4 acc[4][4] = {};

  for (int k0 = 0; k0 < FEAT; k0 += 32){
    bf16x8 a[4], b[4];
    #pragma unroll
    for (int rt=0;rt<4;rt++)
      a[rt] = *reinterpret_cast<const bf16x8*>(&As[rt*16 + l15][k0 + kg*8]);
    #pragma unroll
    for (int t=0;t<4;t++){
      const int n = wave*64 + t*16 + l15;
      b[t] = *reinterpret_cast<const bf16x8*>(Wt + (long)n*FEAT + k0 + kg*8);
    }
    #pragma unroll
    for (int rt=0;rt<4;rt++)
      #pragma unroll
      for (int t=0;t<4;t++)
        acc[rt][t] = __builtin_amdgcn_mfma_f32_16x16x32_bf16(a[rt], b[t], acc[rt][t], 0, 0, 0);
  }

  __syncthreads();

  float p1[4][4] = {}, p2[4][4] = {};
  #pragma unroll
  for (int t=0;t<4;t++){
    const int col = wave*64 + t*16 + l15;
    const float a1 = v1[col];
    const float a2 = v2[col];
    #pragma unroll
    for (int rt=0;rt<4;rt++){
      #pragma unroll
      for (int r=0;r<4;r++){
        const float val = acc[rt][t][r];
        As[rt*16 + kg*4 + r][col] = f2bf(val);
        p1[rt][r] += val * a1;
        p2[rt][r] += val * a2;
      }
    }
  }
  #pragma unroll
  for (int off=1; off<16; off<<=1){
    #pragma unroll
    for (int rt=0;rt<4;rt++)
      #pragma unroll
      for (int r=0;r<4;r++){
        p1[rt][r] += __shfl_xor(p1[rt][r], off, 64);
        p2[rt][r] += __shfl_xor(p2[rt][r], off, 64);
      }
  }
  if (l15 == 0){
    #pragma unroll
    for (int rt=0;rt<4;rt++)
      #pragma unroll
      for (int r=0;r<4;r++){
        atomicAdd(&hgs[rt*16 + kg*4 + r], p1[rt][r]);
        atomicAdd(&sns[rt*16 + kg*4 + r], p2[rt][r]);
      }
  }
  __syncthreads();

  {
    const int c = (tid & 15) << 4;
    #pragma unroll
    for (int i=0;i<4;i++){
      const int r = (tid >> 4) + 16*i;
      if (row0 + r < M){
        const uint4* s = reinterpret_cast<const uint4*>(&As[r][c]);
        uint4* d = reinterpret_cast<uint4*>(Y + (row0 + r)*FEAT + c);
        d[0] = s[0]; d[1] = s[1];
      }
    }
  }
  if (tid < 64 && row0 + tid < M){
    hg[row0 + tid]  = hgs[tid];
    snb[row0 + tid] = sns[tid];
  }
}

// ---------- node attention L1, STANDALONE (half-wave per node, staged loads) ----------
__global__ __launch_bounds__(256) void node_attn1_k(const u16* __restrict__ NE,
    const int* __restrict__ node_list, const float* __restrict__ snb,
    const float* __restrict__ ned, u16* __restrict__ NNo)
{
  const int tid = threadIdx.x;
  const int hl  = tid & 31;
  const int n   = blockIdx.x*8 + (tid >> 5);
  const int c   = hl*8;

  int idx[D_DEG];
  #pragma unroll
  for (int d=0; d<D_DEG; d++) idx[d] = node_list[(long)n*D_DEG + d];
  float nv[D_DEG];
  #pragma unroll
  for (int d=0; d<D_DEG; d++) nv[d] = ned[idx[d]];

  uint4 hb[D_DEG];
  #pragma unroll
  for (int d=0; d<D_DEG; d++)
    hb[d] = *reinterpret_cast<const uint4*>(NE + (long)idx[d]*FEAT + c);

  const float sb = snb[n];
  float w[D_DEG];
  float mx = -1e30f;
  #pragma unroll
  for (int d=0; d<D_DEG; d++){
    float s = lrelu(sb + nv[d]);
    w[d] = s; mx = fmaxf(mx, s);
  }
  float sum = 0.f;
  #pragma unroll
  for (int d=0; d<D_DEG; d++){ w[d] = __expf(w[d]-mx); sum += w[d]; }
  const float inv = 1.f/sum;

  float o[8] = {};
  #pragma unroll
  for (int d=0; d<D_DEG; d++) acc8(o, hb[d], w[d]*inv);

  // layer-2 input activation (ELU) fused here, store bf16
  #pragma unroll
  for (int j=0;j<8;j++) o[j] = eluf(o[j]);
  store_bf8(NNo + (long)n*FEAT + c, o);
}

// ---------- edge attention (pure gather; sb always precomputed) ----------
// SEB_OUT: emit seb_out[e] = elu(bf16(o)) . wE_nxt  (next layer's sb, fused)
template<bool SEB_OUT>
__global__ __launch_bounds__(256) void edge_attn_k(const u16* __restrict__ Hn,
    const int* __restrict__ edge_list,
    const float* __restrict__ hg, const float* __restrict__ an_hi,
    const float* __restrict__ seb_in, const float* __restrict__ wE_nxt,
    float* __restrict__ seb_out,
    u16* __restrict__ NE, float* __restrict__ ned)
{
  const int tid = threadIdx.x;
  const int hl  = tid & 31;
  const int e   = blockIdx.x*8 + (tid >> 5);
  const int c   = hl*8;

  int idx[A_DEG];
  #pragma unroll
  for (int a=0;a<A_DEG;a++) idx[a] = edge_list[e*A_DEG + a];
  float hgv[A_DEG];
  #pragma unroll
  for (int a=0;a<A_DEG;a++) hgv[a] = hg[idx[a]];
  // stage all 6 neighbor rows early
  uint4 hb[A_DEG];
  #pragma unroll
  for (int a=0;a<A_DEG;a++)
    hb[a] = *reinterpret_cast<const uint4*>(Hn + (long)idx[a]*FEAT + c);

  const float sb = seb_in[e];

  float w[A_DEG];
  float mx = -1e30f;
  #pragma unroll
  for (int a=0;a<A_DEG;a++){
    float s = lrelu(sb + hgv[a]);
    w[a] = s; mx = fmaxf(mx, s);
  }
  float sum = 0.f;
  #pragma unroll
  for (int a=0;a<A_DEG;a++){ w[a] = __expf(w[a]-mx); sum += w[a]; }
  const float inv = 1.f/sum;

  float o[8] = {};
  #pragma unroll
  for (int a=0;a<A_DEG;a++) acc8(o, hb[a], w[a]*inv);
  store_bf8(NE + (long)e*FEAT + c, o);

  {
    F8 v = load8(an_hi + c);
    float p = 0.f;
    #pragma unroll
    for (int j=0;j<8;j++) p += o[j]*v.v[j];
    p = half_sum_all(p);
    if (hl == 0) ned[e] = p;
  }
  if (SEB_OUT){
    F8 v = load8(wE_nxt + c);
    float p = 0.f;
    #pragma unroll
    for (int j=0;j<8;j++) p += eluf(bf2f(f2bf(o[j])))*v.v[j];
    p = half_sum_all(p);
    if (hl == 0) seb_out[e] = p;
  }
}

// ---------- FUSED node_attn(L2) + batch assembly ----------
__global__ __launch_bounds__(256) void node_assemble_k(
    const u16* __restrict__ NE, const int* __restrict__ node_list,
    const float* __restrict__ snb, const float* __restrict__ ned,
    const int* __restrict__ batch, float* __restrict__ out)
{
  const int b   = blockIdx.x;
  const int tid = threadIdx.x;
  const int hw  = tid >> 5;     // 0..7
  const int hl  = tid & 31;
  const int c   = hl*8;

  int right = 0;
  #pragma unroll
  for (int cc=0; cc<6; cc++){ if (batch[b*7 + cc] != 0) right = cc+1; }

  if (hw == 6){
    const int e = batch[b*7 + 0];
    F8 x = load8(NE + (long)e*FEAT + c);
    float o[8];
    #pragma unroll
    for (int j=0;j<8;j++) o[j] = eluf(x.v[j]);
    ntstore8(out + ((long)b*7 + 0)*FEAT + c, o);
  } else if (hw < 6){
    const int s  = hw + 1;        // slot 1..6
    float* po = out + ((long)b*7 + s)*FEAT + c;
    if (s < right){
      const int n = batch[b*7 + s];
      int idx[D_DEG];
      #pragma unroll
      for (int d=0; d<D_DEG; d++) idx[d] = node_list[(long)n*D_DEG + d];
      float nv[D_DEG];
      #pragma unroll
      for (int d=0; d<D_DEG; d++) nv[d] = ned[idx[d]];
      const float sb = snb[n];
      float w[D_DEG];
      float mx = -1e30f;
      #pragma unroll
      for (int d=0; d<D_DEG; d++){
        float sc = lrelu(sb + nv[d]);
        w[d] = sc; mx = fmaxf(mx, sc);
      }
      float sum = 0.f;
      #pragma unroll
      for (int d=0; d<D_DEG; d++){ w[d] = __expf(w[d]-mx); sum += w[d]; }
      const float inv = 1.f/sum;

      uint4 hb[D_DEG];
      #pragma unroll
      for (int d=0; d<D_DEG; d++)
        hb[d] = *reinterpret_cast<const uint4*>(NE + (long)idx[d]*FEAT + c);
      float o[8] = {};
      #pragma unroll
      for (int d=0; d<D_DEG; d++) acc8(o, hb[d], w[d]*inv);

      #pragma unroll
      for (int j=0;j<8;j++) o[j] = eluf(o[j]);
      ntstore8(po, o);
    } else {
      float z[8] = {};
      ntstore8(po, z);
    }
  }
}

extern "C" void kernel_launch(void* const* d_in, const int* in_sizes, int n_in,
                              void* d_out, int out_size, void* d_ws, size_t ws_size,
                              hipStream_t stream)
{
  const int*   batch      = (const int*)d_in[0];
  const float* node_embs  = (const float*)d_in[1];
  const float* edge_embs  = (const float*)d_in[2];
  const int*   edge_list  = (const int*)d_in[3];
  const int*   node_list  = (const int*)d_in[4];
  const float* Wn1 = (const float*)d_in[5];
  const float* We1 = (const float*)d_in[6];
  const float* ae1 = (const float*)d_in[7];
  const float* an1 = (const float*)d_in[8];
  const float* Wn2 = (const float*)d_in[9];
  const float* We2 = (const float*)d_in[10];
  const float* ae2 = (const float*)d_in[11];
  const float* an2 = (const float*)d_in[12];
  float* out = (float*)d_out;

  char* ws = (char*)d_ws;
  size_t off = 0;
  auto alloc = [&](size_t bytes)->void* {
    void* p = ws + off; off += (bytes + 255) & ~(size_t)255; return p;
  };
  u16* bHn = (u16*)alloc((size_t)N_NODES*FEAT*2);
  u16* bNE = (u16*)alloc((size_t)N_EDGES*FEAT*2);
  u16* bNN = (u16*)alloc((size_t)N_NODES*FEAT*2);
  u16* Wt1 = (u16*)alloc((size_t)FEAT*FEAT*2);
  u16* Wt2 = (u16*)alloc((size_t)FEAT*FEAT*2);
  float* hg   = (float*)alloc((size_t)N_NODES*4);
  float* snb  = (float*)alloc((size_t)N_NODES*4);
  float* ned  = (float*)alloc((size_t)N_EDGES*4);
  float* seb1 = (float*)alloc((size_t)N_EDGES*4);
  float* seb2 = (float*)alloc((size_t)N_EDGES*4);
  float* wE1  = (float*)alloc(FEAT*4);
  float* wE2  = (float*)alloc(FEAT*4);

  dim3 blk(256);
  const int gemm_grid = (N_NODES + 63) / 64;

  // prep: both transposes + both wvecs in ONE launch
  prep_k<<<dim3(8,8,3), blk, 0, stream>>>(Wn1, Wt1, Wn2, Wt2,
      We1, ae1, wE1, We2, ae2, wE2);

  // sb1: streaming matvec (the only consumer of edge_embs)
  sb1_k<<<N_EDGES/8, blk, 0, stream>>>(edge_embs, wE1, seb1);

  // ---- layer 1 ----
  gemm_mfma_k<float><<<gemm_grid, blk, 0, stream>>>(node_embs, Wt1,
      ae1+FEAT, an1, bHn, hg, snb, N_NODES);
  // L1 edge attention (pure gather); fuses seb2 = elu(bf16(o)) . wE2
  edge_attn_k<true><<<N_EDGES/8, blk, 0, stream>>>(bHn,
      edge_list, hg, an1+FEAT, seb1, wE2, seb2, bNE, ned);

  // ---- node attention L1 (standalone, max gather concurrency) ----
  node_attn1_k<<<N_NODES/8, blk, 0, stream>>>(bNE, node_list, snb, ned, bNN);

  // ---- GEMM layer 2 (reads elu'd NN bf16) + fused rowdots ----
  gemm_mfma_k<u16><<<gemm_grid, blk, 0, stream>>>(bNN, Wt2,
      ae2+FEAT, an2, bHn, hg, snb, N_NODES);

  // ---- layer 2 edge attention (pure gather) ----
  edge_attn_k<false><<<N_EDGES/8, blk, 0, stream>>>(bHn,
      edge_list, hg, an2+FEAT, seb2, nullptr, nullptr, bNE, ned);

  // ---- fused: node_attn(L2) + batch assembly ----
  node_assemble_k<<<BATCH, blk, 0, stream>>>(bNE, node_list, snb, ned, batch, out);
}

// Round 8
// 285.117 us; speedup vs baseline: 1.0448x; 1.0448x over previous
//
#include <hip/hip_runtime.h>
#include <stdint.h>

typedef unsigned short u16;
typedef unsigned int   u32;
typedef __attribute__((ext_vector_type(8))) short bf16x8;   // 8 bf16 (4 VGPRs)
typedef __attribute__((ext_vector_type(4))) float f32x4;    // MFMA C/D

#define N_NODES 30000
#define N_EDGES 60000
#define A_DEG   6
#define D_DEG   16
#define BATCH   4096
#define FEAT    256
#define APAD    8     // LDS pad: (256+8)*2 = 528 B row stride (16B-aligned)

// ---------- bf16 helpers ----------
__device__ __forceinline__ float bfbits2f(u32 hi){ union{u32 u; float f;} v; v.u = hi; return v.f; }
__device__ __forceinline__ float bf2f(u16 h){ return bfbits2f(((u32)h)<<16); }
__device__ __forceinline__ u16 f2bf(float f){
  union{float f; u32 u;} v; v.f = f;
  u32 u = v.u;
  return (u16)((u + 0x7fffu + ((u>>16)&1u)) >> 16);   // RTNE
}

struct F4 { float x,y,z,w; };
struct F8 { float v[8]; };

__device__ __forceinline__ F4 load4(const float* p){
  float4 t = *reinterpret_cast<const float4*>(p);
  F4 f; f.x=t.x; f.y=t.y; f.z=t.z; f.w=t.w; return f;
}
__device__ __forceinline__ F4 load4(const u16* p){
  uint2 u = *reinterpret_cast<const uint2*>(p);
  F4 f;
  f.x = bfbits2f(u.x<<16);
  f.y = bfbits2f(u.x & 0xffff0000u);
  f.z = bfbits2f(u.y<<16);
  f.w = bfbits2f(u.y & 0xffff0000u);
  return f;
}
__device__ __forceinline__ F8 load8(const float* p){
  float4 a = *reinterpret_cast<const float4*>(p);
  float4 b = *reinterpret_cast<const float4*>(p+4);
  F8 f; f.v[0]=a.x; f.v[1]=a.y; f.v[2]=a.z; f.v[3]=a.w;
        f.v[4]=b.x; f.v[5]=b.y; f.v[6]=b.z; f.v[7]=b.w; return f;
}
__device__ __forceinline__ F8 load8(const u16* p){
  uint4 u = *reinterpret_cast<const uint4*>(p);
  F8 f;
  f.v[0]=bfbits2f(u.x<<16); f.v[1]=bfbits2f(u.x&0xffff0000u);
  f.v[2]=bfbits2f(u.y<<16); f.v[3]=bfbits2f(u.y&0xffff0000u);
  f.v[4]=bfbits2f(u.z<<16); f.v[5]=bfbits2f(u.z&0xffff0000u);
  f.v[6]=bfbits2f(u.w<<16); f.v[7]=bfbits2f(u.w&0xffff0000u);
  return f;
}
// accumulate o[0..7] += ww * bf16x8(bits)
__device__ __forceinline__ void acc8(float* o, uint4 u, float ww){
  o[0] += ww*bfbits2f(u.x<<16); o[1] += ww*bfbits2f(u.x&0xffff0000u);
  o[2] += ww*bfbits2f(u.y<<16); o[3] += ww*bfbits2f(u.y&0xffff0000u);
  o[4] += ww*bfbits2f(u.z<<16); o[5] += ww*bfbits2f(u.z&0xffff0000u);
  o[6] += ww*bfbits2f(u.w<<16); o[7] += ww*bfbits2f(u.w&0xffff0000u);
}
__device__ __forceinline__ void store_bf8(u16* p, const float* f){
  uint4 u;
  u.x = (u32)f2bf(f[0]) | ((u32)f2bf(f[1])<<16);
  u.y = (u32)f2bf(f[2]) | ((u32)f2bf(f[3])<<16);
  u.z = (u32)f2bf(f[4]) | ((u32)f2bf(f[5])<<16);
  u.w = (u32)f2bf(f[6]) | ((u32)f2bf(f[7])<<16);
  *reinterpret_cast<uint4*>(p) = u;
}

__device__ __forceinline__ float eluf(float x){ return x > 0.f ? x : (__expf(x) - 1.f); }
__device__ __forceinline__ float lrelu(float x){ return x > 0.f ? x : 0.2f*x; }

__device__ __forceinline__ float wave_sum_lane0(float v){
  #pragma unroll
  for (int off = 32; off > 0; off >>= 1) v += __shfl_down(v, off, 64);
  return v;
}
__device__ __forceinline__ float half_sum_all(float v){   // reduce within 32-lane half
  #pragma unroll
  for (int off = 1; off < 32; off <<= 1) v += __shfl_xor(v, off, 64);
  return v;
}

// ---------- merged prep: z=0/1 -> weight transpose W1/W2; z=2 -> both wvecs ----------
__global__ __launch_bounds__(256) void prep_k(
    const float* __restrict__ Wn1, u16* __restrict__ Wt1,
    const float* __restrict__ Wn2, u16* __restrict__ Wt2,
    const float* __restrict__ We1, const float* __restrict__ ae1, float* __restrict__ wE1,
    const float* __restrict__ We2, const float* __restrict__ ae2, float* __restrict__ wE2)
{
  if (blockIdx.z < 2){
    const float* W = blockIdx.z ? Wn2 : Wn1;
    u16* Wt        = blockIdx.z ? Wt2 : Wt1;
    __shared__ float T[32][33];
    const int bx = blockIdx.x;   // k-tile
    const int by = blockIdx.y;   // n-tile
    const int tc = threadIdx.x & 31;
    const int tr = threadIdx.x >> 5;
    #pragma unroll
    for (int i=0;i<4;i++){
      int r = tr + i*8;
      T[r][tc] = W[(bx*32 + r)*FEAT + by*32 + tc];
    }
    __syncthreads();
    #pragma unroll
    for (int i=0;i<4;i++){
      int r = tr + i*8;
      Wt[(by*32 + r)*FEAT + bx*32 + tc] = f2bf(T[tc][r]);
    }
  } else {
    const int vb   = blockIdx.y*8 + blockIdx.x;       // 0..63
    const int lane = threadIdx.x & 63;
    const int row  = vb*4 + (threadIdx.x >> 6);
    const int c    = lane*4;
    {
      F4 h = load4(We1 + (long)row*FEAT + c);
      F4 a = load4(ae1 + c);
      float p = wave_sum_lane0(h.x*a.x + h.y*a.y + h.z*a.z + h.w*a.w);
      if (lane == 0) wE1[row] = p;
    }
    {
      F4 h = load4(We2 + (long)row*FEAT + c);
      F4 a = load4(ae2 + c);
      float p = wave_sum_lane0(h.x*a.x + h.y*a.y + h.z*a.z + h.w*a.w);
      if (lane == 0) wE2[row] = p;
    }
  }
}

// ---------- MFMA GEMM (64-row tile, 256 threads / 4 waves) + fused rowdots ----------
// Y[M,256](bf16) = X[M,256] @ W via Wt[n][k]; hg=Y·v1, snb=Y·v2.  (L1 only)
__global__ __launch_bounds__(256) void gemm_mfma_k(
    const float* __restrict__ X, const u16* __restrict__ Wt,
    const float* __restrict__ v1, const float* __restrict__ v2,
    u16* __restrict__ Y, float* __restrict__ hg, float* __restrict__ snb,
    int M)
{
  __shared__ u16 As[64][FEAT + APAD];
  __shared__ float hgs[64], sns[64];
  const int tid = threadIdx.x;
  const long row0 = (long)blockIdx.x * 64;

  if (tid < 64){ hgs[tid] = 0.f; sns[tid] = 0.f; }

  {
    const int c = (tid & 15) << 4;
    #pragma unroll
    for (int i=0;i<4;i++){
      const int r = (tid >> 4) + 16*i;
      u16* dst = &As[r][c];
      if (row0 + r < M){
        const float* src = X + (row0 + r)*FEAT + c;
        #pragma unroll
        for (int j=0;j<4;j++){
          F4 v = load4(src + 4*j);
          dst[4*j+0]=f2bf(v.x); dst[4*j+1]=f2bf(v.y);
          dst[4*j+2]=f2bf(v.z); dst[4*j+3]=f2bf(v.w);
        }
      } else {
        #pragma unroll
        for (int j=0;j<16;j++) dst[j] = 0;
      }
    }
  }
  __syncthreads();

  const int wave = tid >> 6;
  const int lane = tid & 63;
  const int l15  = lane & 15;
  const int kg   = lane >> 4;

  f32x4 acc[4][4] = {};

  for (int k0 = 0; k0 < FEAT; k0 += 32){
    bf16x8 a[4], b[4];
    #pragma unroll
    for (int rt=0;rt<4;rt++)
      a[rt] = *reinterpret_cast<const bf16x8*>(&As[rt*16 + l15][k0 + kg*8]);
    #pragma unroll
    for (int t=0;t<4;t++){
      const int n = wave*64 + t*16 + l15;
      b[t] = *reinterpret_cast<const bf16x8*>(Wt + (long)n*FEAT + k0 + kg*8);
    }
    #pragma unroll
    for (int rt=0;rt<4;rt++)
      #pragma unroll
      for (int t=0;t<4;t++)
        acc[rt][t] = __builtin_amdgcn_mfma_f32_16x16x32_bf16(a[rt], b[t], acc[rt][t], 0, 0, 0);
  }

  __syncthreads();

  float p1[4][4] = {}, p2[4][4] = {};
  #pragma unroll
  for (int t=0;t<4;t++){
    const int col = wave*64 + t*16 + l15;
    const float a1 = v1[col];
    const float a2 = v2[col];
    #pragma unroll
    for (int rt=0;rt<4;rt++){
      #pragma unroll
      for (int r=0;r<4;r++){
        const float val = acc[rt][t][r];
        As[rt*16 + kg*4 + r][col] = f2bf(val);
        p1[rt][r] += val * a1;
        p2[rt][r] += val * a2;
      }
    }
  }
  #pragma unroll
  for (int off=1; off<16; off<<=1){
    #pragma unroll
    for (int rt=0;rt<4;rt++)
      #pragma unroll
      for (int r=0;r<4;r++){
        p1[rt][r] += __shfl_xor(p1[rt][r], off, 64);
        p2[rt][r] += __shfl_xor(p2[rt][r], off, 64);
      }
  }
  if (l15 == 0){
    #pragma unroll
    for (int rt=0;rt<4;rt++)
      #pragma unroll
      for (int r=0;r<4;r++){
        atomicAdd(&hgs[rt*16 + kg*4 + r], p1[rt][r]);
        atomicAdd(&sns[rt*16 + kg*4 + r], p2[rt][r]);
      }
  }
  __syncthreads();

  {
    const int c = (tid & 15) << 4;
    #pragma unroll
    for (int i=0;i<4;i++){
      const int r = (tid >> 4) + 16*i;
      if (row0 + r < M){
        const uint4* s = reinterpret_cast<const uint4*>(&As[r][c]);
        uint4* d = reinterpret_cast<uint4*>(Y + (row0 + r)*FEAT + c);
        d[0] = s[0]; d[1] = s[1];
      }
    }
  }
  if (tid < 64 && row0 + tid < M){
    hg[row0 + tid]  = hgs[tid];
    snb[row0 + tid] = sns[tid];
  }
}

// ---------- FUSED node_attn(L1) + gemm(L2), 64-row tile, 256 threads ----------
// Round-4 proven form: single-row deep-staged gather (VGPR 104, under the 128
// cliff), then MFMA phase.  snb1 read before snb2 overwrite is safe (own rows).
__global__ __launch_bounds__(256) void node_gemm_k(
    const u16* __restrict__ NE, const int* __restrict__ node_list,
    const float* __restrict__ snb1, const float* __restrict__ ned,
    const u16* __restrict__ Wt,
    const float* __restrict__ v1, const float* __restrict__ v2,
    u16* __restrict__ Y, float* __restrict__ hg, float* __restrict__ snb2,
    int M)
{
  __shared__ u16 As[64][FEAT + APAD];
  __shared__ float hgs[64], sns[64];
  const int tid = threadIdx.x;
  const long row0 = (long)blockIdx.x * 64;

  if (tid < 64){ hgs[tid] = 0.f; sns[tid] = 0.f; }

  // ---- phase 1: gather-attention into LDS ----
  const int hw = tid >> 5;      // half-wave 0..7
  const int hl = tid & 31;
  const int c  = hl*8;
  #pragma unroll
  for (int i=0;i<8;i++){
    const int r = hw*8 + i;
    const long n = row0 + r;
    u16* dst = &As[r][c];
    if (n < M){
      int idx[D_DEG];
      #pragma unroll
      for (int d=0; d<D_DEG; d++) idx[d] = node_list[n*D_DEG + d];
      float nv[D_DEG];
      #pragma unroll
      for (int d=0; d<D_DEG; d++) nv[d] = ned[idx[d]];   // 16 loads in flight
      const float sb = snb1[n];
      float w[D_DEG];
      float mx = -1e30f;
      #pragma unroll
      for (int d=0; d<D_DEG; d++){
        float s = lrelu(sb + nv[d]);
        w[d] = s; mx = fmaxf(mx, s);
      }
      float sum = 0.f;
      #pragma unroll
      for (int d=0; d<D_DEG; d++){ w[d] = __expf(w[d]-mx); sum += w[d]; }
      const float inv = 1.f/sum;

      // stage ALL 16 row loads as raw bits, then convert+accumulate
      uint4 hb[D_DEG];
      #pragma unroll
      for (int d=0; d<D_DEG; d++)
        hb[d] = *reinterpret_cast<const uint4*>(NE + (long)idx[d]*FEAT + c);
      float o[8] = {};
      #pragma unroll
      for (int d=0; d<D_DEG; d++) acc8(o, hb[d], w[d]*inv);

      // apply ELU (layer-2 input activation), convert to bf16
      #pragma unroll
      for (int j=0;j<8;j++) dst[j] = f2bf(eluf(o[j]));
    } else {
      #pragma unroll
      for (int j=0;j<8;j++) dst[j] = 0;
    }
  }
  __syncthreads();

  // ---- phase 2: MFMA ----
  const int wave = tid >> 6;
  const int lane = tid & 63;
  const int l15  = lane & 15;
  const int kg   = lane >> 4;

  f32x4 acc[4][4] = {};

  for (int k0 = 0; k0 < FEAT; k0 += 32){
    bf16x8 a[4], b[4];
    #pragma unroll
    for (int rt=0;rt<4;rt++)
      a[rt] = *reinterpret_cast<const bf16x8*>(&As[rt*16 + l15][k0 + kg*8]);
    #pragma unroll
    for (int t=0;t<4;t++){
      const int n = wave*64 + t*16 + l15;
      b[t] = *reinterpret_cast<const bf16x8*>(Wt + (long)n*FEAT + k0 + kg*8);
    }
    #pragma unroll
    for (int rt=0;rt<4;rt++)
      #pragma unroll
      for (int t=0;t<4;t++)
        acc[rt][t] = __builtin_amdgcn_mfma_f32_16x16x32_bf16(a[rt], b[t], acc[rt][t], 0, 0, 0);
  }

  __syncthreads();

  float p1[4][4] = {}, p2[4][4] = {};
  #pragma unroll
  for (int t=0;t<4;t++){
    const int col = wave*64 + t*16 + l15;
    const float a1 = v1[col];
    const float a2 = v2[col];
    #pragma unroll
    for (int rt=0;rt<4;rt++){
      #pragma unroll
      for (int r=0;r<4;r++){
        const float val = acc[rt][t][r];
        As[rt*16 + kg*4 + r][col] = f2bf(val);
        p1[rt][r] += val * a1;
        p2[rt][r] += val * a2;
      }
    }
  }
  #pragma unroll
  for (int off=1; off<16; off<<=1){
    #pragma unroll
    for (int rt=0;rt<4;rt++)
      #pragma unroll
      for (int r=0;r<4;r++){
        p1[rt][r] += __shfl_xor(p1[rt][r], off, 64);
        p2[rt][r] += __shfl_xor(p2[rt][r], off, 64);
      }
  }
  if (l15 == 0){
    #pragma unroll
    for (int rt=0;rt<4;rt++)
      #pragma unroll
      for (int r=0;r<4;r++){
        atomicAdd(&hgs[rt*16 + kg*4 + r], p1[rt][r]);
        atomicAdd(&sns[rt*16 + kg*4 + r], p2[rt][r]);
      }
  }
  __syncthreads();

  {
    const int cc = (tid & 15) << 4;
    #pragma unroll
    for (int i=0;i<4;i++){
      const int r = (tid >> 4) + 16*i;
      if (row0 + r < M){
        const uint4* s = reinterpret_cast<const uint4*>(&As[r][cc]);
        uint4* d = reinterpret_cast<uint4*>(Y + (row0 + r)*FEAT + cc);
        d[0] = s[0]; d[1] = s[1];
      }
    }
  }
  if (tid < 64 && row0 + tid < M){
    hg[row0 + tid]   = hgs[tid];
    snb2[row0 + tid] = sns[tid];
  }
}

// ---------- edge attention ----------
// SB_PRE:  read precomputed sb scalar (skip the Xe stream entirely)
// SEB_OUT: emit seb_out[e] = elu(bf16(o)) . wE_nxt  (next layer's sb, fused)
template<bool SB_PRE, bool SEB_OUT>
__global__ __launch_bounds__(256) void edge_attn_k(const u16* __restrict__ Hn,
    const float* __restrict__ Xe, const float* __restrict__ wE,
    const int* __restrict__ edge_list,
    const float* __restrict__ hg, const float* __restrict__ an_hi,
    const float* __restrict__ seb_in, const float* __restrict__ wE_nxt,
    float* __restrict__ seb_out,
    u16* __restrict__ NE, float* __restrict__ ned)
{
  const int tid = threadIdx.x;
  const int hl  = tid & 31;
  const int e   = blockIdx.x*8 + (tid >> 5);
  const int c   = hl*8;

  int idx[A_DEG];
  #pragma unroll
  for (int a=0;a<A_DEG;a++) idx[a] = edge_list[e*A_DEG + a];
  float hgv[A_DEG];
  #pragma unroll
  for (int a=0;a<A_DEG;a++) hgv[a] = hg[idx[a]];
  // stage all 6 neighbor rows early
  uint4 hb[A_DEG];
  #pragma unroll
  for (int a=0;a<A_DEG;a++)
    hb[a] = *reinterpret_cast<const uint4*>(Hn + (long)idx[a]*FEAT + c);

  float sb;
  if (SB_PRE){
    sb = seb_in[e];
  } else {
    F8 x = load8(Xe + (long)e*FEAT + c);
    F8 v = load8(wE + c);
    float p = 0.f;
    #pragma unroll
    for (int j=0;j<8;j++) p += x.v[j]*v.v[j];
    sb = half_sum_all(p);
  }

  float w[A_DEG];
  float mx = -1e30f;
  #pragma unroll
  for (int a=0;a<A_DEG;a++){
    float s = lrelu(sb + hgv[a]);
    w[a] = s; mx = fmaxf(mx, s);
  }
  float sum = 0.f;
  #pragma unroll
  for (int a=0;a<A_DEG;a++){ w[a] = __expf(w[a]-mx); sum += w[a]; }
  const float inv = 1.f/sum;

  float o[8] = {};
  #pragma unroll
  for (int a=0;a<A_DEG;a++) acc8(o, hb[a], w[a]*inv);
  store_bf8(NE + (long)e*FEAT + c, o);

  {
    F8 v = load8(an_hi + c);
    float p = 0.f;
    #pragma unroll
    for (int j=0;j<8;j++) p += o[j]*v.v[j];
    p = half_sum_all(p);
    if (hl == 0) ned[e] = p;
  }
  if (SEB_OUT){
    F8 v = load8(wE_nxt + c);
    float p = 0.f;
    #pragma unroll
    for (int j=0;j<8;j++) p += eluf(bf2f(f2bf(o[j])))*v.v[j];
    p = half_sum_all(p);
    if (hl == 0) seb_out[e] = p;
  }
}

// ---------- FUSED node_attn(L2) + batch assembly ----------
__global__ __launch_bounds__(256) void node_assemble_k(
    const u16* __restrict__ NE, const int* __restrict__ node_list,
    const float* __restrict__ snb, const float* __restrict__ ned,
    const int* __restrict__ batch, float* __restrict__ out)
{
  const int b   = blockIdx.x;
  const int tid = threadIdx.x;
  const int hw  = tid >> 5;     // 0..7
  const int hl  = tid & 31;
  const int c   = hl*8;

  int right = 0;
  #pragma unroll
  for (int cc=0; cc<6; cc++){ if (batch[b*7 + cc] != 0) right = cc+1; }

  if (hw == 6){
    const int e = batch[b*7 + 0];
    F8 x = load8(NE + (long)e*FEAT + c);
    float4 o0, o1;
    o0.x=eluf(x.v[0]); o0.y=eluf(x.v[1]); o0.z=eluf(x.v[2]); o0.w=eluf(x.v[3]);
    o1.x=eluf(x.v[4]); o1.y=eluf(x.v[5]); o1.z=eluf(x.v[6]); o1.w=eluf(x.v[7]);
    float* po = out + ((long)b*7 + 0)*FEAT + c;
    *reinterpret_cast<float4*>(po)   = o0;
    *reinterpret_cast<float4*>(po+4) = o1;
  } else if (hw < 6){
    const int s  = hw + 1;        // slot 1..6
    float* po = out + ((long)b*7 + s)*FEAT + c;
    if (s < right){
      const int n = batch[b*7 + s];
      int idx[D_DEG];
      #pragma unroll
      for (int d=0; d<D_DEG; d++) idx[d] = node_list[(long)n*D_DEG + d];
      float nv[D_DEG];
      #pragma unroll
      for (int d=0; d<D_DEG; d++) nv[d] = ned[idx[d]];
      const float sb = snb[n];
      float w[D_DEG];
      float mx = -1e30f;
      #pragma unroll
      for (int d=0; d<D_DEG; d++){
        float sc = lrelu(sb + nv[d]);
        w[d] = sc; mx = fmaxf(mx, sc);
      }
      float sum = 0.f;
      #pragma unroll
      for (int d=0; d<D_DEG; d++){ w[d] = __expf(w[d]-mx); sum += w[d]; }
      const float inv = 1.f/sum;

      uint4 hb[D_DEG];
      #pragma unroll
      for (int d=0; d<D_DEG; d++)
        hb[d] = *reinterpret_cast<const uint4*>(NE + (long)idx[d]*FEAT + c);
      float o[8] = {};
      #pragma unroll
      for (int d=0; d<D_DEG; d++) acc8(o, hb[d], w[d]*inv);

      float4 o0, o1;
      o0.x=eluf(o[0]); o0.y=eluf(o[1]); o0.z=eluf(o[2]); o0.w=eluf(o[3]);
      o1.x=eluf(o[4]); o1.y=eluf(o[5]); o1.z=eluf(o[6]); o1.w=eluf(o[7]);
      *reinterpret_cast<float4*>(po)   = o0;
      *reinterpret_cast<float4*>(po+4) = o1;
    } else {
      float4 z; z.x=0.f; z.y=0.f; z.z=0.f; z.w=0.f;
      *reinterpret_cast<float4*>(po)   = z;
      *reinterpret_cast<float4*>(po+4) = z;
    }
  }
}

extern "C" void kernel_launch(void* const* d_in, const int* in_sizes, int n_in,
                              void* d_out, int out_size, void* d_ws, size_t ws_size,
                              hipStream_t stream)
{
  const int*   batch      = (const int*)d_in[0];
  const float* node_embs  = (const float*)d_in[1];
  const float* edge_embs  = (const float*)d_in[2];
  const int*   edge_list  = (const int*)d_in[3];
  const int*   node_list  = (const int*)d_in[4];
  const float* Wn1 = (const float*)d_in[5];
  const float* We1 = (const float*)d_in[6];
  const float* ae1 = (const float*)d_in[7];
  const float* an1 = (const float*)d_in[8];
  const float* Wn2 = (const float*)d_in[9];
  const float* We2 = (const float*)d_in[10];
  const float* ae2 = (const float*)d_in[11];
  const float* an2 = (const float*)d_in[12];
  float* out = (float*)d_out;

  char* ws = (char*)d_ws;
  size_t off = 0;
  auto alloc = [&](size_t bytes)->void* {
    void* p = ws + off; off += (bytes + 255) & ~(size_t)255; return p;
  };
  u16* bHn = (u16*)alloc((size_t)N_NODES*FEAT*2);
  u16* bNE = (u16*)alloc((size_t)N_EDGES*FEAT*2);
  u16* Wt1 = (u16*)alloc((size_t)FEAT*FEAT*2);
  u16* Wt2 = (u16*)alloc((size_t)FEAT*FEAT*2);
  float* hg   = (float*)alloc((size_t)N_NODES*4);
  float* snb  = (float*)alloc((size_t)N_NODES*4);
  float* ned  = (float*)alloc((size_t)N_EDGES*4);
  float* seb2 = (float*)alloc((size_t)N_EDGES*4);
  float* wE1  = (float*)alloc(FEAT*4);
  float* wE2  = (float*)alloc(FEAT*4);

  dim3 blk(256);
  const int gemm_grid = (N_NODES + 63) / 64;

  // prep: both transposes + both wvecs in ONE launch
  prep_k<<<dim3(8,8,3), blk, 0, stream>>>(Wn1, Wt1, Wn2, Wt2,
      We1, ae1, wE1, We2, ae2, wE2);

  // ---- layer 1 ----
  gemm_mfma_k<<<gemm_grid, blk, 0, stream>>>(node_embs, Wt1,
      ae1+FEAT, an1, bHn, hg, snb, N_NODES);
  // L1 edge attention (sb from Xe stream, overlapped); fuses seb2 for layer 2
  edge_attn_k<false,true><<<N_EDGES/8, blk, 0, stream>>>(bHn, edge_embs, wE1,
      edge_list, hg, an1+FEAT, nullptr, wE2, seb2, bNE, ned);

  // ---- fused: node_attn(L1) + gemm(L2) ----
  node_gemm_k<<<gemm_grid, blk, 0, stream>>>(bNE, node_list, snb, ned,
      Wt2, ae2+FEAT, an2, bHn, hg, snb, N_NODES);

  // ---- layer 2 edge attention (sb precomputed; no bNE re-stream) ----
  edge_attn_k<true,false><<<N_EDGES/8, blk, 0, stream>>>(bHn, nullptr, nullptr,
      edge_list, hg, an2+FEAT, seb2, nullptr, nullptr, bNE, ned);

  // ---- fused: node_attn(L2) + batch assembly ----
  node_assemble_k<<<BATCH, blk, 0, stream>>>(bNE, node_list, snb, ned, batch, out);
}

// Round 9
// 284.105 us; speedup vs baseline: 1.0486x; 1.0036x over previous
//
#include <hip/hip_runtime.h>
#include <stdint.h>

typedef unsigned short u16;
typedef unsigned int   u32;
typedef __attribute__((ext_vector_type(8))) short bf16x8;   // 8 bf16 (4 VGPRs)
typedef __attribute__((ext_vector_type(4))) float f32x4;    // MFMA C/D

#define N_NODES 30000
#define N_EDGES 60000
#define A_DEG   6
#define D_DEG   16
#define BATCH   4096
#define FEAT    256
#define APAD    8       // LDS pad: (256+8)*2 = 528 B row stride (16B-aligned)
#define GEMM_GRID ((N_NODES + 63) / 64)   // 469
#define SB_GRID   (N_EDGES / 8)           // 7500

// ---------- bf16 helpers ----------
__device__ __forceinline__ float bfbits2f(u32 hi){ union{u32 u; float f;} v; v.u = hi; return v.f; }
__device__ __forceinline__ float bf2f(u16 h){ return bfbits2f(((u32)h)<<16); }
__device__ __forceinline__ u16 f2bf(float f){
  union{float f; u32 u;} v; v.f = f;
  u32 u = v.u;
  return (u16)((u + 0x7fffu + ((u>>16)&1u)) >> 16);   // RTNE
}

struct F4 { float x,y,z,w; };
struct F8 { float v[8]; };

__device__ __forceinline__ F4 load4(const float* p){
  float4 t = *reinterpret_cast<const float4*>(p);
  F4 f; f.x=t.x; f.y=t.y; f.z=t.z; f.w=t.w; return f;
}
__device__ __forceinline__ F4 load4(const u16* p){
  uint2 u = *reinterpret_cast<const uint2*>(p);
  F4 f;
  f.x = bfbits2f(u.x<<16);
  f.y = bfbits2f(u.x & 0xffff0000u);
  f.z = bfbits2f(u.y<<16);
  f.w = bfbits2f(u.y & 0xffff0000u);
  return f;
}
__device__ __forceinline__ F8 load8(const float* p){
  float4 a = *reinterpret_cast<const float4*>(p);
  float4 b = *reinterpret_cast<const float4*>(p+4);
  F8 f; f.v[0]=a.x; f.v[1]=a.y; f.v[2]=a.z; f.v[3]=a.w;
        f.v[4]=b.x; f.v[5]=b.y; f.v[6]=b.z; f.v[7]=b.w; return f;
}
__device__ __forceinline__ F8 load8(const u16* p){
  uint4 u = *reinterpret_cast<const uint4*>(p);
  F8 f;
  f.v[0]=bfbits2f(u.x<<16); f.v[1]=bfbits2f(u.x&0xffff0000u);
  f.v[2]=bfbits2f(u.y<<16); f.v[3]=bfbits2f(u.y&0xffff0000u);
  f.v[4]=bfbits2f(u.z<<16); f.v[5]=bfbits2f(u.z&0xffff0000u);
  f.v[6]=bfbits2f(u.w<<16); f.v[7]=bfbits2f(u.w&0xffff0000u);
  return f;
}
// accumulate o[0..7] += ww * bf16x8(bits)
__device__ __forceinline__ void acc8(float* o, uint4 u, float ww){
  o[0] += ww*bfbits2f(u.x<<16); o[1] += ww*bfbits2f(u.x&0xffff0000u);
  o[2] += ww*bfbits2f(u.y<<16); o[3] += ww*bfbits2f(u.y&0xffff0000u);
  o[4] += ww*bfbits2f(u.z<<16); o[5] += ww*bfbits2f(u.z&0xffff0000u);
  o[6] += ww*bfbits2f(u.w<<16); o[7] += ww*bfbits2f(u.w&0xffff0000u);
}
__device__ __forceinline__ void store_bf8(u16* p, const float* f){
  uint4 u;
  u.x = (u32)f2bf(f[0]) | ((u32)f2bf(f[1])<<16);
  u.y = (u32)f2bf(f[2]) | ((u32)f2bf(f[3])<<16);
  u.z = (u32)f2bf(f[4]) | ((u32)f2bf(f[5])<<16);
  u.w = (u32)f2bf(f[6]) | ((u32)f2bf(f[7])<<16);
  *reinterpret_cast<uint4*>(p) = u;
}

__device__ __forceinline__ float eluf(float x){ return x > 0.f ? x : (__expf(x) - 1.f); }
__device__ __forceinline__ float lrelu(float x){ return x > 0.f ? x : 0.2f*x; }

__device__ __forceinline__ float wave_sum_lane0(float v){
  #pragma unroll
  for (int off = 32; off > 0; off >>= 1) v += __shfl_down(v, off, 64);
  return v;
}
__device__ __forceinline__ float half_sum_all(float v){   // reduce within 32-lane half
  #pragma unroll
  for (int off = 1; off < 32; off <<= 1) v += __shfl_xor(v, off, 64);
  return v;
}

// ---------- merged prep: z=0/1 -> weight transpose W1/W2; z=2 -> both wvecs ----------
__global__ __launch_bounds__(256) void prep_k(
    const float* __restrict__ Wn1, u16* __restrict__ Wt1,
    const float* __restrict__ Wn2, u16* __restrict__ Wt2,
    const float* __restrict__ We1, const float* __restrict__ ae1, float* __restrict__ wE1,
    const float* __restrict__ We2, const float* __restrict__ ae2, float* __restrict__ wE2)
{
  if (blockIdx.z < 2){
    const float* W = blockIdx.z ? Wn2 : Wn1;
    u16* Wt        = blockIdx.z ? Wt2 : Wt1;
    __shared__ float T[32][33];
    const int bx = blockIdx.x;   // k-tile
    const int by = blockIdx.y;   // n-tile
    const int tc = threadIdx.x & 31;
    const int tr = threadIdx.x >> 5;
    #pragma unroll
    for (int i=0;i<4;i++){
      int r = tr + i*8;
      T[r][tc] = W[(bx*32 + r)*FEAT + by*32 + tc];
    }
    __syncthreads();
    #pragma unroll
    for (int i=0;i<4;i++){
      int r = tr + i*8;
      Wt[(by*32 + r)*FEAT + bx*32 + tc] = f2bf(T[tc][r]);
    }
  } else {
    const int vb   = blockIdx.y*8 + blockIdx.x;       // 0..63
    const int lane = threadIdx.x & 63;
    const int row  = vb*4 + (threadIdx.x >> 6);
    const int c    = lane*4;
    {
      F4 h = load4(We1 + (long)row*FEAT + c);
      F4 a = load4(ae1 + c);
      float p = wave_sum_lane0(h.x*a.x + h.y*a.y + h.z*a.z + h.w*a.w);
      if (lane == 0) wE1[row] = p;
    }
    {
      F4 h = load4(We2 + (long)row*FEAT + c);
      F4 a = load4(ae2 + c);
      float p = wave_sum_lane0(h.x*a.x + h.y*a.y + h.z*a.z + h.w*a.w);
      if (lane == 0) wE2[row] = p;
    }
  }
}

// ---------- MFMA GEMM (L1) + CO-SCHEDULED sb1 streaming matvec ----------
// Blocks [0, GEMM_GRID):      Y = X @ W (MFMA) + fused rowdots (hg, snb)
// Blocks [GEMM_GRID, +SB_GRID): seb1[e] = edge_embs[e,:] . wE1
// The 61 MB Xe stream rides the GEMM's idle HBM bandwidth instead of
// competing with edge_attn's gather (r7 showed serializing it costs ~8 us).
__global__ __launch_bounds__(256) void gemm_sb_k(
    const float* __restrict__ X, const u16* __restrict__ Wt,
    const float* __restrict__ v1, const float* __restrict__ v2,
    u16* __restrict__ Y, float* __restrict__ hg, float* __restrict__ snb,
    int M,
    const float* __restrict__ Xe, const float* __restrict__ wEv,
    float* __restrict__ seb)
{
  __shared__ u16 As[64][FEAT + APAD];
  __shared__ float hgs[64], sns[64];
  const int tid = threadIdx.x;

  if (blockIdx.x >= GEMM_GRID){
    // ---- sb1 streaming branch (no barrier crossed; block-uniform) ----
    const int eb = blockIdx.x - GEMM_GRID;
    const int hl = tid & 31;
    const int e  = eb*8 + (tid >> 5);
    const int c  = hl*8;
    F8 x = load8(Xe + (long)e*FEAT + c);
    F8 v = load8(wEv + c);
    float p = 0.f;
    #pragma unroll
    for (int j=0;j<8;j++) p += x.v[j]*v.v[j];
    p = half_sum_all(p);
    if (hl == 0) seb[e] = p;
    return;
  }

  const long row0 = (long)blockIdx.x * 64;

  if (tid < 64){ hgs[tid] = 0.f; sns[tid] = 0.f; }

  {
    const int c = (tid & 15) << 4;
    #pragma unroll
    for (int i=0;i<4;i++){
      const int r = (tid >> 4) + 16*i;
      u16* dst = &As[r][c];
      if (row0 + r < M){
        const float* src = X + (row0 + r)*FEAT + c;
        #pragma unroll
        for (int j=0;j<4;j++){
          F4 v = load4(src + 4*j);
          dst[4*j+0]=f2bf(v.x); dst[4*j+1]=f2bf(v.y);
          dst[4*j+2]=f2bf(v.z); dst[4*j+3]=f2bf(v.w);
        }
      } else {
        #pragma unroll
        for (int j=0;j<16;j++) dst[j] = 0;
      }
    }
  }
  __syncthreads();

  const int wave = tid >> 6;
  const int lane = tid & 63;
  const int l15  = lane & 15;
  const int kg   = lane >> 4;

  f32x4 acc[4][4] = {};

  for (int k0 = 0; k0 < FEAT; k0 += 32){
    bf16x8 a[4], b[4];
    #pragma unroll
    for (int rt=0;rt<4;rt++)
      a[rt] = *reinterpret_cast<const bf16x8*>(&As[rt*16 + l15][k0 + kg*8]);
    #pragma unroll
    for (int t=0;t<4;t++){
      const int n = wave*64 + t*16 + l15;
      b[t] = *reinterpret_cast<const bf16x8*>(Wt + (long)n*FEAT + k0 + kg*8);
    }
    #pragma unroll
    for (int rt=0;rt<4;rt++)
      #pragma unroll
      for (int t=0;t<4;t++)
        acc[rt][t] = __builtin_amdgcn_mfma_f32_16x16x32_bf16(a[rt], b[t], acc[rt][t], 0, 0, 0);
  }

  __syncthreads();

  float p1[4][4] = {}, p2[4][4] = {};
  #pragma unroll
  for (int t=0;t<4;t++){
    const int col = wave*64 + t*16 + l15;
    const float a1 = v1[col];
    const float a2 = v2[col];
    #pragma unroll
    for (int rt=0;rt<4;rt++){
      #pragma unroll
      for (int r=0;r<4;r++){
        const float val = acc[rt][t][r];
        As[rt*16 + kg*4 + r][col] = f2bf(val);
        p1[rt][r] += val * a1;
        p2[rt][r] += val * a2;
      }
    }
  }
  #pragma unroll
  for (int off=1; off<16; off<<=1){
    #pragma unroll
    for (int rt=0;rt<4;rt++)
      #pragma unroll
      for (int r=0;r<4;r++){
        p1[rt][r] += __shfl_xor(p1[rt][r], off, 64);
        p2[rt][r] += __shfl_xor(p2[rt][r], off, 64);
      }
  }
  if (l15 == 0){
    #pragma unroll
    for (int rt=0;rt<4;rt++)
      #pragma unroll
      for (int r=0;r<4;r++){
        atomicAdd(&hgs[rt*16 + kg*4 + r], p1[rt][r]);
        atomicAdd(&sns[rt*16 + kg*4 + r], p2[rt][r]);
      }
  }
  __syncthreads();

  {
    const int c = (tid & 15) << 4;
    #pragma unroll
    for (int i=0;i<4;i++){
      const int r = (tid >> 4) + 16*i;
      if (row0 + r < M){
        const uint4* s = reinterpret_cast<const uint4*>(&As[r][c]);
        uint4* d = reinterpret_cast<uint4*>(Y + (row0 + r)*FEAT + c);
        d[0] = s[0]; d[1] = s[1];
      }
    }
  }
  if (tid < 64 && row0 + tid < M){
    hg[row0 + tid]  = hgs[tid];
    snb[row0 + tid] = sns[tid];
  }
}

// ---------- FUSED node_attn(L1) + gemm(L2), 64-row tile, 256 threads ----------
// Round-4 proven form: single-row deep-staged gather (VGPR 104, under the 128
// cliff), then MFMA phase.  snb1 read before snb2 overwrite is safe (own rows).
__global__ __launch_bounds__(256) void node_gemm_k(
    const u16* __restrict__ NE, const int* __restrict__ node_list,
    const float* __restrict__ snb1, const float* __restrict__ ned,
    const u16* __restrict__ Wt,
    const float* __restrict__ v1, const float* __restrict__ v2,
    u16* __restrict__ Y, float* __restrict__ hg, float* __restrict__ snb2,
    int M)
{
  __shared__ u16 As[64][FEAT + APAD];
  __shared__ float hgs[64], sns[64];
  const int tid = threadIdx.x;
  const long row0 = (long)blockIdx.x * 64;

  if (tid < 64){ hgs[tid] = 0.f; sns[tid] = 0.f; }

  // ---- phase 1: gather-attention into LDS ----
  const int hw = tid >> 5;      // half-wave 0..7
  const int hl = tid & 31;
  const int c  = hl*8;
  #pragma unroll
  for (int i=0;i<8;i++){
    const int r = hw*8 + i;
    const long n = row0 + r;
    u16* dst = &As[r][c];
    if (n < M){
      int idx[D_DEG];
      #pragma unroll
      for (int d=0; d<D_DEG; d++) idx[d] = node_list[n*D_DEG + d];
      float nv[D_DEG];
      #pragma unroll
      for (int d=0; d<D_DEG; d++) nv[d] = ned[idx[d]];   // 16 loads in flight
      const float sb = snb1[n];
      float w[D_DEG];
      float mx = -1e30f;
      #pragma unroll
      for (int d=0; d<D_DEG; d++){
        float s = lrelu(sb + nv[d]);
        w[d] = s; mx = fmaxf(mx, s);
      }
      float sum = 0.f;
      #pragma unroll
      for (int d=0; d<D_DEG; d++){ w[d] = __expf(w[d]-mx); sum += w[d]; }
      const float inv = 1.f/sum;

      // stage ALL 16 row loads as raw bits, then convert+accumulate
      uint4 hb[D_DEG];
      #pragma unroll
      for (int d=0; d<D_DEG; d++)
        hb[d] = *reinterpret_cast<const uint4*>(NE + (long)idx[d]*FEAT + c);
      float o[8] = {};
      #pragma unroll
      for (int d=0; d<D_DEG; d++) acc8(o, hb[d], w[d]*inv);

      // apply ELU (layer-2 input activation), convert to bf16
      #pragma unroll
      for (int j=0;j<8;j++) dst[j] = f2bf(eluf(o[j]));
    } else {
      #pragma unroll
      for (int j=0;j<8;j++) dst[j] = 0;
    }
  }
  __syncthreads();

  // ---- phase 2: MFMA ----
  const int wave = tid >> 6;
  const int lane = tid & 63;
  const int l15  = lane & 15;
  const int kg   = lane >> 4;

  f32x4 acc[4][4] = {};

  for (int k0 = 0; k0 < FEAT; k0 += 32){
    bf16x8 a[4], b[4];
    #pragma unroll
    for (int rt=0;rt<4;rt++)
      a[rt] = *reinterpret_cast<const bf16x8*>(&As[rt*16 + l15][k0 + kg*8]);
    #pragma unroll
    for (int t=0;t<4;t++){
      const int n = wave*64 + t*16 + l15;
      b[t] = *reinterpret_cast<const bf16x8*>(Wt + (long)n*FEAT + k0 + kg*8);
    }
    #pragma unroll
    for (int rt=0;rt<4;rt++)
      #pragma unroll
      for (int t=0;t<4;t++)
        acc[rt][t] = __builtin_amdgcn_mfma_f32_16x16x32_bf16(a[rt], b[t], acc[rt][t], 0, 0, 0);
  }

  __syncthreads();

  float p1[4][4] = {}, p2[4][4] = {};
  #pragma unroll
  for (int t=0;t<4;t++){
    const int col = wave*64 + t*16 + l15;
    const float a1 = v1[col];
    const float a2 = v2[col];
    #pragma unroll
    for (int rt=0;rt<4;rt++){
      #pragma unroll
      for (int r=0;r<4;r++){
        const float val = acc[rt][t][r];
        As[rt*16 + kg*4 + r][col] = f2bf(val);
        p1[rt][r] += val * a1;
        p2[rt][r] += val * a2;
      }
    }
  }
  #pragma unroll
  for (int off=1; off<16; off<<=1){
    #pragma unroll
    for (int rt=0;rt<4;rt++)
      #pragma unroll
      for (int r=0;r<4;r++){
        p1[rt][r] += __shfl_xor(p1[rt][r], off, 64);
        p2[rt][r] += __shfl_xor(p2[rt][r], off, 64);
      }
  }
  if (l15 == 0){
    #pragma unroll
    for (int rt=0;rt<4;rt++)
      #pragma unroll
      for (int r=0;r<4;r++){
        atomicAdd(&hgs[rt*16 + kg*4 + r], p1[rt][r]);
        atomicAdd(&sns[rt*16 + kg*4 + r], p2[rt][r]);
      }
  }
  __syncthreads();

  {
    const int cc = (tid & 15) << 4;
    #pragma unroll
    for (int i=0;i<4;i++){
      const int r = (tid >> 4) + 16*i;
      if (row0 + r < M){
        const uint4* s = reinterpret_cast<const uint4*>(&As[r][cc]);
        uint4* d = reinterpret_cast<uint4*>(Y + (row0 + r)*FEAT + cc);
        d[0] = s[0]; d[1] = s[1];
      }
    }
  }
  if (tid < 64 && row0 + tid < M){
    hg[row0 + tid]   = hgs[tid];
    snb2[row0 + tid] = sns[tid];
  }
}

// ---------- edge attention (pure gather; sb precomputed) ----------
// SEB_OUT: emit seb_out[e] = elu(bf16(o)) . wE_nxt  (next layer's sb, fused)
template<bool SEB_OUT>
__global__ __launch_bounds__(256) void edge_attn_k(const u16* __restrict__ Hn,
    const int* __restrict__ edge_list,
    const float* __restrict__ hg, const float* __restrict__ an_hi,
    const float* __restrict__ seb_in, const float* __restrict__ wE_nxt,
    float* __restrict__ seb_out,
    u16* __restrict__ NE, float* __restrict__ ned)
{
  const int tid = threadIdx.x;
  const int hl  = tid & 31;
  const int e   = blockIdx.x*8 + (tid >> 5);
  const int c   = hl*8;

  int idx[A_DEG];
  #pragma unroll
  for (int a=0;a<A_DEG;a++) idx[a] = edge_list[e*A_DEG + a];
  float hgv[A_DEG];
  #pragma unroll
  for (int a=0;a<A_DEG;a++) hgv[a] = hg[idx[a]];
  // stage all 6 neighbor rows early
  uint4 hb[A_DEG];
  #pragma unroll
  for (int a=0;a<A_DEG;a++)
    hb[a] = *reinterpret_cast<const uint4*>(Hn + (long)idx[a]*FEAT + c);

  const float sb = seb_in[e];

  float w[A_DEG];
  float mx = -1e30f;
  #pragma unroll
  for (int a=0;a<A_DEG;a++){
    float s = lrelu(sb + hgv[a]);
    w[a] = s; mx = fmaxf(mx, s);
  }
  float sum = 0.f;
  #pragma unroll
  for (int a=0;a<A_DEG;a++){ w[a] = __expf(w[a]-mx); sum += w[a]; }
  const float inv = 1.f/sum;

  float o[8] = {};
  #pragma unroll
  for (int a=0;a<A_DEG;a++) acc8(o, hb[a], w[a]*inv);
  store_bf8(NE + (long)e*FEAT + c, o);

  {
    F8 v = load8(an_hi + c);
    float p = 0.f;
    #pragma unroll
    for (int j=0;j<8;j++) p += o[j]*v.v[j];
    p = half_sum_all(p);
    if (hl == 0) ned[e] = p;
  }
  if (SEB_OUT){
    F8 v = load8(wE_nxt + c);
    float p = 0.f;
    #pragma unroll
    for (int j=0;j<8;j++) p += eluf(bf2f(f2bf(o[j])))*v.v[j];
    p = half_sum_all(p);
    if (hl == 0) seb_out[e] = p;
  }
}

// ---------- FUSED node_attn(L2) + batch assembly ----------
__global__ __launch_bounds__(256) void node_assemble_k(
    const u16* __restrict__ NE, const int* __restrict__ node_list,
    const float* __restrict__ snb, const float* __restrict__ ned,
    const int* __restrict__ batch, float* __restrict__ out)
{
  const int b   = blockIdx.x;
  const int tid = threadIdx.x;
  const int hw  = tid >> 5;     // 0..7
  const int hl  = tid & 31;
  const int c   = hl*8;

  int right = 0;
  #pragma unroll
  for (int cc=0; cc<6; cc++){ if (batch[b*7 + cc] != 0) right = cc+1; }

  if (hw == 6){
    const int e = batch[b*7 + 0];
    F8 x = load8(NE + (long)e*FEAT + c);
    float4 o0, o1;
    o0.x=eluf(x.v[0]); o0.y=eluf(x.v[1]); o0.z=eluf(x.v[2]); o0.w=eluf(x.v[3]);
    o1.x=eluf(x.v[4]); o1.y=eluf(x.v[5]); o1.z=eluf(x.v[6]); o1.w=eluf(x.v[7]);
    float* po = out + ((long)b*7 + 0)*FEAT + c;
    *reinterpret_cast<float4*>(po)   = o0;
    *reinterpret_cast<float4*>(po+4) = o1;
  } else if (hw < 6){
    const int s  = hw + 1;        // slot 1..6
    float* po = out + ((long)b*7 + s)*FEAT + c;
    if (s < right){
      const int n = batch[b*7 + s];
      int idx[D_DEG];
      #pragma unroll
      for (int d=0; d<D_DEG; d++) idx[d] = node_list[(long)n*D_DEG + d];
      float nv[D_DEG];
      #pragma unroll
      for (int d=0; d<D_DEG; d++) nv[d] = ned[idx[d]];
      const float sb = snb[n];
      float w[D_DEG];
      float mx = -1e30f;
      #pragma unroll
      for (int d=0; d<D_DEG; d++){
        float sc = lrelu(sb + nv[d]);
        w[d] = sc; mx = fmaxf(mx, sc);
      }
      float sum = 0.f;
      #pragma unroll
      for (int d=0; d<D_DEG; d++){ w[d] = __expf(w[d]-mx); sum += w[d]; }
      const float inv = 1.f/sum;

      uint4 hb[D_DEG];
      #pragma unroll
      for (int d=0; d<D_DEG; d++)
        hb[d] = *reinterpret_cast<const uint4*>(NE + (long)idx[d]*FEAT + c);
      float o[8] = {};
      #pragma unroll
      for (int d=0; d<D_DEG; d++) acc8(o, hb[d], w[d]*inv);

      float4 o0, o1;
      o0.x=eluf(o[0]); o0.y=eluf(o[1]); o0.z=eluf(o[2]); o0.w=eluf(o[3]);
      o1.x=eluf(o[4]); o1.y=eluf(o[5]); o1.z=eluf(o[6]); o1.w=eluf(o[7]);
      *reinterpret_cast<float4*>(po)   = o0;
      *reinterpret_cast<float4*>(po+4) = o1;
    } else {
      float4 z; z.x=0.f; z.y=0.f; z.z=0.f; z.w=0.f;
      *reinterpret_cast<float4*>(po)   = z;
      *reinterpret_cast<float4*>(po+4) = z;
    }
  }
}

extern "C" void kernel_launch(void* const* d_in, const int* in_sizes, int n_in,
                              void* d_out, int out_size, void* d_ws, size_t ws_size,
                              hipStream_t stream)
{
  const int*   batch      = (const int*)d_in[0];
  const float* node_embs  = (const float*)d_in[1];
  const float* edge_embs  = (const float*)d_in[2];
  const int*   edge_list  = (const int*)d_in[3];
  const int*   node_list  = (const int*)d_in[4];
  const float* Wn1 = (const float*)d_in[5];
  const float* We1 = (const float*)d_in[6];
  const float* ae1 = (const float*)d_in[7];
  const float* an1 = (const float*)d_in[8];
  const float* Wn2 = (const float*)d_in[9];
  const float* We2 = (const float*)d_in[10];
  const float* ae2 = (const float*)d_in[11];
  const float* an2 = (const float*)d_in[12];
  float* out = (float*)d_out;

  char* ws = (char*)d_ws;
  size_t off = 0;
  auto alloc = [&](size_t bytes)->void* {
    void* p = ws + off; off += (bytes + 255) & ~(size_t)255; return p;
  };
  u16* bHn = (u16*)alloc((size_t)N_NODES*FEAT*2);
  u16* bNE = (u16*)alloc((size_t)N_EDGES*FEAT*2);
  u16* Wt1 = (u16*)alloc((size_t)FEAT*FEAT*2);
  u16* Wt2 = (u16*)alloc((size_t)FEAT*FEAT*2);
  float* hg   = (float*)alloc((size_t)N_NODES*4);
  float* snb  = (float*)alloc((size_t)N_NODES*4);
  float* ned  = (float*)alloc((size_t)N_EDGES*4);
  float* seb1 = (float*)alloc((size_t)N_EDGES*4);
  float* seb2 = (float*)alloc((size_t)N_EDGES*4);
  float* wE1  = (float*)alloc(FEAT*4);
  float* wE2  = (float*)alloc(FEAT*4);

  dim3 blk(256);

  // prep: both transposes + both wvecs in ONE launch
  prep_k<<<dim3(8,8,3), blk, 0, stream>>>(Wn1, Wt1, Wn2, Wt2,
      We1, ae1, wE1, We2, ae2, wE2);

  // ---- layer 1: GEMM + co-scheduled sb1 stream (one launch) ----
  gemm_sb_k<<<GEMM_GRID + SB_GRID, blk, 0, stream>>>(node_embs, Wt1,
      ae1+FEAT, an1, bHn, hg, snb, N_NODES,
      edge_embs, wE1, seb1);

  // L1 edge attention (pure gather, sb precomputed); fuses seb2 for layer 2
  edge_attn_k<true><<<N_EDGES/8, blk, 0, stream>>>(bHn,
      edge_list, hg, an1+FEAT, seb1, wE2, seb2, bNE, ned);

  // ---- fused: node_attn(L1) + gemm(L2) ----
  node_gemm_k<<<GEMM_GRID, blk, 0, stream>>>(bNE, node_list, snb, ned,
      Wt2, ae2+FEAT, an2, bHn, hg, snb, N_NODES);

  // ---- layer 2 edge attention (sb precomputed; no bNE re-stream) ----
  edge_attn_k<false><<<N_EDGES/8, blk, 0, stream>>>(bHn,
      edge_list, hg, an2+FEAT, seb2, nullptr, nullptr, bNE, ned);

  // ---- fused: node_attn(L2) + batch assembly ----
  node_assemble_k<<<BATCH, blk, 0, stream>>>(bNE, node_list, snb, ned, batch, out);
}